// Round 11
// baseline (345.530 us; speedup 1.0000x reference)
//
#include <hip/hip_runtime.h>

typedef _Float16 f16x8 __attribute__((ext_vector_type(8)));
typedef _Float16 f16x2 __attribute__((ext_vector_type(2)));
typedef float f32x4 __attribute__((ext_vector_type(4)));
typedef float f32x8 __attribute__((ext_vector_type(8)));

#define N_NODES 50000
#define N_EDGES 800000
#define MAXDEG 64
#define NODE_STRIDE 3072          // grid 768 blocks x 4 waves
#define BA_OFF 0
#define BV_OFF (N_NODES * 64)

// ---- workspace layout (byte offsets)
#define REC_OFF   0ull            // 50000*128 fp16 = 12.8 MB node records
#define CNT_OFF   12800000ull     // 50000 int degree counts
#define ELLP_OFF  13200384ull     // 50000*64 int eid slots = 12.8 MB

// ---- LDS weight layout (ushort units, fp16). K=64 rows padded to 72, K=32 to 40
// Rows of WFOLD sigma-permuted, rows of WCAT/WM1/WM2/WM3 sigma2-permuted so
// every MFMA C-output lands directly in the B-fragment layout of its consumer.
#define OFF_WFOLD 0              // 32 x 40
#define OFF_WCAT  1280           // 64 x 72  [WY000 | WY110]
#define OFF_W011  5888           // 16 x 40
#define OFF_WV    6528           // 16 x 72  [WY101 | WY111]
#define OFF_WM1   7680           // 64 x 72
#define OFF_WM2   12288
#define OFF_WM3   16896
#define W_USHORTS 21504

__device__ __forceinline__ unsigned short f2h(float x) {
    _Float16 h = (_Float16)x;
    union { _Float16 h; unsigned short u; } c; c.h = h;
    return c.u;
}
__device__ __forceinline__ f16x2 pkrtz(float a, float b) {
    auto r = __builtin_amdgcn_cvt_pkrtz(a, b);   // __fp16 ext_vector(2)
    union { decltype(r) i; f16x2 o; } c; c.i = r;
    return c.o;
}
__device__ __forceinline__ f16x2 as_h2(unsigned u) {
    union { unsigned u; f16x2 h; } c; c.u = u; return c.h;
}
__device__ __forceinline__ unsigned h2_pack(float a, float b) {
    union { f16x2 h; unsigned u; } c;
    c.h = pkrtz(a, b);
    return c.u;
}
__device__ __forceinline__ f16x8 mk8(f16x2 a, f16x2 b, f16x2 c, f16x2 d) {
    union { f16x2 p[4]; f16x8 v; } u;
    u.p[0] = a; u.p[1] = b; u.p[2] = c; u.p[3] = d;
    return u.v;
}
__device__ __forceinline__ f16x8 as_f16x8(uint4 q) {
    union { uint4 u; f16x8 h; } c; c.u = q; return c.h;
}
// packed leaky-relu on 2 halves
__device__ __forceinline__ f16x2 leaky2(f16x2 x) {
    return __builtin_elementwise_max(x, x * (_Float16)0.1f);
}

// ---------------- fused pre-pass: node features + ELL build in one dispatch.
// ELL slot = 4B edge-id only (dst/r recovered by gather in the main kernel):
// a node's ~16 slots fit in ONE 64B line -> 4x fewer scattered lines than the
// old 16B slots, and the edge phase carries no r_ij/dst traffic at all.
// cnt zeroed by hipMemsetAsync before launch. 4 edges/thread for ILP.
__global__ __launch_bounds__(256) void pre_kernel(
    const float* __restrict__ x_a, const float* __restrict__ x_v,
    const float* __restrict__ W_L0, const float* __restrict__ W_L1,
    const int* __restrict__ src,
    unsigned short* __restrict__ rec, int* __restrict__ cnt,
    int* __restrict__ ellp)
{
    int b = blockIdx.x;
    if (b % 9 == 0) {
        // ---- edge block: 782 blocks x 256 threads x 4 edges
        int base = (b / 9) * 1024 + threadIdx.x;
#pragma unroll
        for (int k = 0; k < 4; ++k) {
            int e = base + k * 256;
            if (e < N_EDGES) {
                int s = src[e];
                int o = atomicAdd(&cnt[s], 1);
                if (o < MAXDEG) ellp[(size_t)s * MAXDEG + o] = e;
            }
        }
    } else {
        // ---- node block: fp16 node records (float4-vectorized)
        int nb = b - (b / 9 + 1);              // 6250 node blocks
        int t = nb * 256 + threadIdx.x;
        int n = t >> 5, c = t & 31;
        const float4* xa = (const float4*)(x_a + (size_t)n * 64);
        const float4* w0 = (const float4*)(W_L0 + (size_t)c * 64);
        float accA = 0.f;
#pragma unroll
        for (int k = 0; k < 16; ++k) {
            float4 a = xa[k], w = w0[k];
            accA += a.x * w.x + a.y * w.y + a.z * w.z + a.w * w.w;
        }
        const float4* xv = (const float4*)(x_v + (size_t)n * 48);
        const float* w1 = W_L1 + c * 16;
        float a0 = 0.f, a1 = 0.f, a2 = 0.f;
#pragma unroll
        for (int g = 0; g < 4; ++g) {
            float4 v0 = xv[g * 3 + 0], v1 = xv[g * 3 + 1], v2 = xv[g * 3 + 2];
            float wA = w1[g * 4 + 0], wB = w1[g * 4 + 1], wC = w1[g * 4 + 2], wD = w1[g * 4 + 3];
            a0 += v0.x * wA; a1 += v0.y * wA; a2 += v0.z * wA;
            a0 += v0.w * wB; a1 += v1.x * wB; a2 += v1.y * wB;
            a0 += v1.z * wC; a1 += v1.w * wC; a2 += v2.x * wC;
            a0 += v2.y * wD; a1 += v2.z * wD; a2 += v2.w * wD;
        }
        unsigned short* rp = rec + (size_t)n * 128;
        rp[c]      = f2h(accA);
        rp[32 + c] = f2h(a0);
        rp[64 + c] = f2h(a1);
        rp[96 + c] = f2h(a2);
    }
}

// ---------------- node-major fused kernel: fp16 packed-math edition.
// ELL gives eid only; dst[eid] (L2-resident 3.2MB) and r_ij[eid] (L3-resident
// 9.6MB) are gathered one tile ahead: eid load at tile start, dst/r gather
// after phi, rec-quad gather after psi_a — three dependent prefetch stages
// spread across the ~1.9Kcy tile. r stays f32: numerics unchanged.
// __launch_bounds__(256, 1): raising the bound makes the allocator spill
// (r1/r2 regression). VGPR must stay <= 170 for 3 waves/SIMD.
__global__ __launch_bounds__(256, 1) void node_major_kernel(
    const int* __restrict__ ellp,
    const float* __restrict__ r_ij, const int* __restrict__ dst,
    const float* __restrict__ W_enc, const float* __restrict__ b_enc,
    const float* __restrict__ WY000, const float* __restrict__ WY110,
    const float* __restrict__ WY011, const float* __restrict__ WY101, const float* __restrict__ WY111,
    const float* __restrict__ Wm1, const float* __restrict__ bm1,
    const float* __restrict__ Wm2, const float* __restrict__ bm2,
    const float* __restrict__ Wm3,
    const unsigned short* __restrict__ rec,
    const int* __restrict__ cnt,
    float* __restrict__ out)
{
    __shared__ __align__(16) unsigned short Wlds[W_USHORTS];
    __shared__ __align__(8) unsigned BiasH[80];   // 160 f16 biases as f16x2 pairs

    const int tid = threadIdx.x;

    // ---- stage weights to LDS (fp16), fold W_enc over duplicated coeffs.
    // sigma  (32-chan): row i holds chan  c = ((i>>2)&3)*8 + (i>>4)*4 + (i&3)
    // sigma2 (64-dim) : row i holds dim   d = (i>>5)*32 + ((i>>2)&3)*8 + ((i>>4)&1)*4 + (i&3)
    for (int idx = tid; idx < 1024; idx += 256) {
        int i = idx >> 5, k = idx & 31;
        int c = ((i >> 2) & 3) * 8 + (i >> 4) * 4 + (i & 3);
        float v;
        if (k < 16) v = W_enc[c * 64 + 2 * k] + W_enc[c * 64 + 2 * k + 1];
        else        v = W_enc[c * 64 + 32 + 2 * (k - 16)] + W_enc[c * 64 + 32 + 2 * (k - 16) + 1];
        Wlds[OFF_WFOLD + i * 40 + k] = f2h(v);
    }
    for (int idx = tid; idx < 4096; idx += 256) {
        int i = idx >> 6, k = idx & 63;
        int d = (i >> 5) * 32 + ((i >> 2) & 3) * 8 + ((i >> 4) & 1) * 4 + (i & 3);
        float v = (k < 32) ? WY000[d * 32 + k] : WY110[d * 32 + (k - 32)];
        Wlds[OFF_WCAT + i * 72 + k] = f2h(v);
        Wlds[OFF_WM1 + i * 72 + k] = f2h(Wm1[d * 64 + k]);
        Wlds[OFF_WM2 + i * 72 + k] = f2h(Wm2[d * 64 + k]);
        Wlds[OFF_WM3 + i * 72 + k] = f2h(Wm3[d * 64 + k]);
    }
    for (int idx = tid; idx < 512; idx += 256) {
        int vv = idx >> 5, k = idx & 31;
        Wlds[OFF_W011 + vv * 40 + k] = f2h(WY011[vv * 32 + k]);
    }
    for (int idx = tid; idx < 1024; idx += 256) {
        int vv = idx >> 6, k = idx & 63;
        float w = (k < 32) ? WY101[vv * 32 + k] : WY111[vv * 32 + (k - 32)];
        Wlds[OFF_WV + vv * 72 + k] = f2h(w);
    }
    if (tid < 80) {
        float bv[2];
#pragma unroll
        for (int p = 0; p < 2; ++p) {
            int i = tid * 2 + p;
            float v;
            if (i < 32) {
                int c = ((i >> 2) & 3) * 8 + (i >> 4) * 4 + (i & 3);
                v = b_enc[c];
            } else {
                int ii = (i < 96) ? (i - 32) : (i - 96);
                int d = (ii >> 5) * 32 + ((ii >> 2) & 3) * 8 + ((ii >> 4) & 1) * 4 + (ii & 3);
                v = (i < 96) ? bm1[d] : bm2[d];
            }
            bv[p] = v;
        }
        BiasH[tid] = h2_pack(bv[0], bv[1]);
    }
    __syncthreads();

    const int wid  = tid >> 6;
    const int lane = tid & 63;
    const int col  = lane & 15;
    const int quad = lane >> 4;

    const f32x4 zero = {0.f, 0.f, 0.f, 0.f};
    float* __restrict__ outA = out + BA_OFF;
    float* __restrict__ outV = out + BV_OFF;

    // ---- hoist loop-invariant fragments (12 VGPR): W011 + WV
    const f16x8 a011R = *(const f16x8*)&Wlds[OFF_W011 + col * 40 + quad * 8];
    const f16x8 av0R  = *(const f16x8*)&Wlds[OFF_WV + col * 72 + quad * 8];
    const f16x8 av1R  = *(const f16x8*)&Wlds[OFF_WV + col * 72 + 32 + quad * 8];

    // ---- prologue: serial version of the 3-stage gather chain
    int n_cur = blockIdx.x * 4 + wid, j_cur = 0;
    int deg_cur = cnt[n_cur]; deg_cur = (deg_cur < MAXDEG) ? deg_cur : MAXDEG;
    float rC0, rC1, rC2;
    uint4 qaN, qv0N, qv1N, qv2N;
    {
        int e0 = ellp[(size_t)n_cur * MAXDEG + col];
        unsigned ue = ((unsigned)e0 < N_EDGES) ? (unsigned)e0 : 0u;
        rC0 = r_ij[ue * 3 + 0];
        rC1 = r_ij[ue * 3 + 1];
        rC2 = r_ij[ue * 3 + 2];
        int dc = dst[ue];
        int ndc = ((unsigned)dc < N_NODES) ? dc : 0;
        const uint4* rp0 = (const uint4*)(rec + (size_t)ndc * 128);
        qaN  = rp0[quad];
        qv0N = rp0[4 + quad];
        qv1N = rp0[8 + quad];
        qv2N = rp0[12 + quad];
    }
    int n_nxt, j_nxt;
    if (16 < deg_cur) { n_nxt = n_cur; j_nxt = 16; } else { n_nxt = n_cur + NODE_STRIDE; j_nxt = 0; }

    float accA[4][4];
    float accV[12];
#pragma unroll
    for (int mt = 0; mt < 4; ++mt)
#pragma unroll
        for (int r = 0; r < 4; ++r) accA[mt][r] = 0.f;
#pragma unroll
    for (int j = 0; j < 12; ++j) accV[j] = 0.f;

    while (n_cur < N_NODES) {
        // ---- consume prefetched rec quads + r (issued last tile)
        f16x8 la  = as_f16x8(qaN);
        f16x8 lv0 = as_f16x8(qv0N);
        f16x8 lv1 = as_f16x8(qv1N);
        f16x8 lv2 = as_f16x8(qv2N);

        // ---- stage A: next-tile head eid (4B coalesced) + next deg
        int ns = (n_nxt < N_NODES) ? n_nxt : 0;
        int eidN = ellp[(size_t)ns * MAXDEG + j_nxt + col];
        int dnx = cnt[ns]; dnx = (dnx < MAXDEG) ? dnx : MAXDEG;

        const float validf = (j_cur + col < deg_cur) ? 1.f : 0.f;
        const float vf01 = 0.1f * validf;
        const _Float16 vh = (_Float16)validf;
        const f16x2 vh2 = {vh, vh};

        // ---- per-edge geometry (fast transcendentals) on f32 r
        float r0 = rC0, r1 = rC1, r2 = rC2;
        float u  = sqrtf(r0 * r0 + r1 * r1 + r2 * r2);
        float a  = 0.6283185307f * u;            // (pi/5) * dist
        float s14 = 1.4f * u;
        float e2 = __expf(fminf(2.f * s14, 20.f));
        float f  = (e2 - 1.f) / ((e2 + 1.f) * fmaxf(s14, 1e-12f));
        float rh0 = 1.4f * r0 * f, rh1 = 1.4f * r1 * f, rh2 = 1.4f * r2 * f;
        _Float16 h0 = (_Float16)rh0, h1 = (_Float16)rh1, h2 = (_Float16)rh2;

        // ---- radial features: native sincos + dual-chain recurrence
        float c1, s1;
        __sincosf(a, &s1, &c1);
        float c2 = c1 * c1 - s1 * s1, s2 = 2.f * c1 * s1;
        float cc, ss;
        if (quad & 1) {
            float c4 = c2 * c2 - s2 * s2, s4 = 2.f * c2 * s2;
            float c8 = c4 * c4 - s4 * s4, s8 = 2.f * c4 * s4;
            cc = c8 * c1 - s8 * s1; ss = s8 * c1 + c8 * s1;   // harmonic 9
        } else { cc = c1; ss = s1; }                           // harmonic 1
        float ca = cc, sa = ss;
        float cb = cc * c1 - ss * s1, sb = ss * c1 + cc * s1;
        bool usec = (quad < 2);
        f32x8 rvf;
        rvf[0] = usec ? ca : sa;
        rvf[1] = usec ? cb : sb;
#pragma unroll
        for (int st = 0; st < 3; ++st) {
            float can = ca * c2 - sa * s2; sa = sa * c2 + ca * s2; ca = can;
            float cbn = cb * c2 - sb * s2; sb = sb * c2 + cb * s2; cb = cbn;
            rvf[2 + 2 * st] = usec ? ca : sa;
            rvf[3 + 2 * st] = usec ? cb : sb;
        }
        f16x8 brad = mk8(pkrtz(rvf[0], rvf[1]), pkrtz(rvf[2], rvf[3]),
                         pkrtz(rvf[4], rvf[5]), pkrtz(rvf[6], rvf[7]));

        // ---- phi GEMM: output lands as chans quad*8+j (sigma-permuted A rows)
        f16x8 phi8;
        {
            f16x8 aw0 = *(const f16x8*)&Wlds[OFF_WFOLD + col * 40 + quad * 8];
            f32x4 pa = __builtin_amdgcn_mfma_f32_16x16x32_f16(aw0, brad, zero, 0, 0, 0);
            f16x8 aw1 = *(const f16x8*)&Wlds[OFF_WFOLD + (16 + col) * 40 + quad * 8];
            f32x4 pb = __builtin_amdgcn_mfma_f32_16x16x32_f16(aw1, brad, zero, 0, 0, 0);
            uint2 b0 = *(const uint2*)&BiasH[quad * 2];
            uint2 b1 = *(const uint2*)&BiasH[8 + quad * 2];
            f16x2 p01 = (pkrtz(pa[0], pa[1]) + as_h2(b0.x)) * vh2;
            f16x2 p23 = (pkrtz(pa[2], pa[3]) + as_h2(b0.y)) * vh2;
            f16x2 p45 = (pkrtz(pb[0], pb[1]) + as_h2(b1.x)) * vh2;
            f16x2 p67 = (pkrtz(pb[2], pb[3]) + as_h2(b1.y)) * vh2;
            phi8 = mk8(p01, p23, p45, p67);
        }

        // ---- stage B: gather next-tile r + dst (eidN returned by now)
        unsigned ueN = ((unsigned)eidN < N_EDGES) ? (unsigned)eidN : 0u;
        float rN0 = r_ij[ueN * 3 + 0];
        float rN1 = r_ij[ueN * 3 + 1];
        float rN2 = r_ij[ueN * 3 + 2];
        int dN = dst[ueN];

        // ---- packed tensor products (v_pk_*_f16): plv shared by y1 and psi_v
        f16x8 plv0 = phi8 * lv0;
        f16x8 plv1 = phi8 * lv1;
        f16x8 plv2 = phi8 * lv2;
        f16x8 fy0 = la * phi8;                       // y000
        f16x8 fy1 = plv0 * h0 + plv1 * h1 + plv2 * h2;   // y110 = phi*(lv.rh)

        // ---- psi_a (output sigma2-permuted via WCAT row permutation)
        f32x4 pacc[4];
#pragma unroll
        for (int mt = 0; mt < 4; ++mt) {
            f16x8 a0 = *(const f16x8*)&Wlds[OFF_WCAT + (mt * 16 + col) * 72 + quad * 8];
            f16x8 a1 = *(const f16x8*)&Wlds[OFF_WCAT + (mt * 16 + col) * 72 + 32 + quad * 8];
            pacc[mt] = __builtin_amdgcn_mfma_f32_16x16x32_f16(a0, fy0, zero, 0, 0, 0);
            pacc[mt] = __builtin_amdgcn_mfma_f32_16x16x32_f16(a1, fy1, pacc[mt], 0, 0, 0);
        }
#pragma unroll
        for (int mt = 0; mt < 4; ++mt)
#pragma unroll
            for (int r = 0; r < 4; ++r)
                accA[mt][r] = fmaf(pacc[mt][r], vf01, accA[mt][r]);
        // psi -> MLP B fragments (dims quad*8+j and 32+quad*8+j)
        f16x8 fb0 = mk8(pkrtz(pacc[0][0], pacc[0][1]), pkrtz(pacc[0][2], pacc[0][3]),
                        pkrtz(pacc[1][0], pacc[1][1]), pkrtz(pacc[1][2], pacc[1][3]));
        f16x8 fb1 = mk8(pkrtz(pacc[2][0], pacc[2][1]), pkrtz(pacc[2][2], pacc[2][3]),
                        pkrtz(pacc[3][0], pacc[3][1]), pkrtz(pacc[3][2], pacc[3][3]));

        // ---- stage C: gather next-tile rec quads (dN returned by now)
        {
            int ndn = ((unsigned)dN < N_NODES) ? dN : 0;
            const uint4* rpn = (const uint4*)(rec + (size_t)ndn * 128);
            qaN  = rpn[quad];
            qv0N = rpn[4 + quad];
            qv1N = rpn[8 + quad];
            qv2N = rpn[12 + quad];
        }

        // ---- t011 (hoisted A fragment)
        f32x4 t011v = __builtin_amdgcn_mfma_f32_16x16x32_f16(a011R, fy0, zero, 0, 0, 0);
        f32x4 t01s;
#pragma unroll
        for (int r = 0; r < 4; ++r) t01s[r] = 0.1f * t011v[r];

        // ---- psi_v: q1 = plv (free), q2 = packed cross of plv with rh
        {
            f16x8 q2x = plv1 * h2 - plv2 * h1;
            f32x4 vx = __builtin_amdgcn_mfma_f32_16x16x32_f16(av0R, plv0, zero, 0, 0, 0);
            vx = __builtin_amdgcn_mfma_f32_16x16x32_f16(av1R, q2x, vx, 0, 0, 0);
#pragma unroll
            for (int r = 0; r < 4; ++r)
                accV[r * 3 + 0] = fmaf(0.1f, vx[r], fmaf(t01s[r], rh0, accV[r * 3 + 0]));

            f16x8 q2y = plv2 * h0 - plv0 * h2;
            f32x4 vy = __builtin_amdgcn_mfma_f32_16x16x32_f16(av0R, plv1, zero, 0, 0, 0);
            vy = __builtin_amdgcn_mfma_f32_16x16x32_f16(av1R, q2y, vy, 0, 0, 0);
#pragma unroll
            for (int r = 0; r < 4; ++r)
                accV[r * 3 + 1] = fmaf(0.1f, vy[r], fmaf(t01s[r], rh1, accV[r * 3 + 1]));

            f16x8 q2z = plv0 * h1 - plv1 * h0;
            f32x4 vz = __builtin_amdgcn_mfma_f32_16x16x32_f16(av0R, plv2, zero, 0, 0, 0);
            vz = __builtin_amdgcn_mfma_f32_16x16x32_f16(av1R, q2z, vz, 0, 0, 0);
#pragma unroll
            for (int r = 0; r < 4; ++r)
                accV[r * 3 + 2] = fmaf(0.1f, vz[r], fmaf(t01s[r], rh2, accV[r * 3 + 2]));
        }

        // ---- residual MLP (rows sigma2-permuted => register chaining)
        f32x4 hacc[4];
#pragma unroll
        for (int mt = 0; mt < 4; ++mt) {
            f16x8 a0 = *(const f16x8*)&Wlds[OFF_WM1 + (mt * 16 + col) * 72 + quad * 8];
            f16x8 a1 = *(const f16x8*)&Wlds[OFF_WM1 + (mt * 16 + col) * 72 + 32 + quad * 8];
            hacc[mt] = __builtin_amdgcn_mfma_f32_16x16x32_f16(a0, fb0, zero, 0, 0, 0);
            hacc[mt] = __builtin_amdgcn_mfma_f32_16x16x32_f16(a1, fb1, hacc[mt], 0, 0, 0);
        }
        f16x8 fh0, fh1;
        {
            uint2 bA = *(const uint2*)&BiasH[16 + 0 * 8 + quad * 2];
            uint2 bB = *(const uint2*)&BiasH[16 + 1 * 8 + quad * 2];
            uint2 bC = *(const uint2*)&BiasH[16 + 2 * 8 + quad * 2];
            uint2 bD = *(const uint2*)&BiasH[16 + 3 * 8 + quad * 2];
            fh0 = mk8(leaky2(pkrtz(hacc[0][0], hacc[0][1]) + as_h2(bA.x)),
                      leaky2(pkrtz(hacc[0][2], hacc[0][3]) + as_h2(bA.y)),
                      leaky2(pkrtz(hacc[1][0], hacc[1][1]) + as_h2(bB.x)),
                      leaky2(pkrtz(hacc[1][2], hacc[1][3]) + as_h2(bB.y)));
            fh1 = mk8(leaky2(pkrtz(hacc[2][0], hacc[2][1]) + as_h2(bC.x)),
                      leaky2(pkrtz(hacc[2][2], hacc[2][3]) + as_h2(bC.y)),
                      leaky2(pkrtz(hacc[3][0], hacc[3][1]) + as_h2(bD.x)),
                      leaky2(pkrtz(hacc[3][2], hacc[3][3]) + as_h2(bD.y)));
        }

        f32x4 gacc[4];
#pragma unroll
        for (int mt = 0; mt < 4; ++mt) {
            f16x8 a0 = *(const f16x8*)&Wlds[OFF_WM2 + (mt * 16 + col) * 72 + quad * 8];
            f16x8 a1 = *(const f16x8*)&Wlds[OFF_WM2 + (mt * 16 + col) * 72 + 32 + quad * 8];
            gacc[mt] = __builtin_amdgcn_mfma_f32_16x16x32_f16(a0, fh0, zero, 0, 0, 0);
            gacc[mt] = __builtin_amdgcn_mfma_f32_16x16x32_f16(a1, fh1, gacc[mt], 0, 0, 0);
        }
        f16x8 fg0, fg1;
        {
            // bm2 biases live at BiasH[48..80)
            uint2 bA = *(const uint2*)&BiasH[48 + 0 * 8 + quad * 2];
            uint2 bB = *(const uint2*)&BiasH[48 + 1 * 8 + quad * 2];
            uint2 bC = *(const uint2*)&BiasH[48 + 2 * 8 + quad * 2];
            uint2 bD = *(const uint2*)&BiasH[48 + 3 * 8 + quad * 2];
            fg0 = mk8(leaky2(pkrtz(gacc[0][0], gacc[0][1]) + as_h2(bA.x)),
                      leaky2(pkrtz(gacc[0][2], gacc[0][3]) + as_h2(bA.y)),
                      leaky2(pkrtz(gacc[1][0], gacc[1][1]) + as_h2(bB.x)),
                      leaky2(pkrtz(gacc[1][2], gacc[1][3]) + as_h2(bB.y)));
            fg1 = mk8(leaky2(pkrtz(gacc[2][0], gacc[2][1]) + as_h2(bC.x)),
                      leaky2(pkrtz(gacc[2][2], gacc[2][3]) + as_h2(bC.y)),
                      leaky2(pkrtz(gacc[3][0], gacc[3][1]) + as_h2(bD.x)),
                      leaky2(pkrtz(gacc[3][2], gacc[3][3]) + as_h2(bD.y)));
        }

#pragma unroll
        for (int mt = 0; mt < 4; ++mt) {
            f16x8 a0 = *(const f16x8*)&Wlds[OFF_WM3 + (mt * 16 + col) * 72 + quad * 8];
            f16x8 a1 = *(const f16x8*)&Wlds[OFF_WM3 + (mt * 16 + col) * 72 + 32 + quad * 8];
            f32x4 oacc = __builtin_amdgcn_mfma_f32_16x16x32_f16(a0, fg0, zero, 0, 0, 0);
            oacc = __builtin_amdgcn_mfma_f32_16x16x32_f16(a1, fg1, oacc, 0, 0, 0);
#pragma unroll
            for (int r = 0; r < 4; ++r)
                accA[mt][r] = fmaf(oacc[r], vf01, accA[mt][r]);
        }

        // ---- node boundary: DPP reduce over the 16 cols + store + reset
        if (n_nxt != n_cur) {
#pragma unroll
            for (int mt = 0; mt < 4; ++mt)
#pragma unroll
                for (int r = 0; r < 4; ++r) {
                    float x = accA[mt][r];
                    int t0 = __builtin_amdgcn_update_dpp(0, __float_as_int(x), 0xB1, 0xf, 0xf, true);
                    x += __int_as_float(t0);
                    int t1 = __builtin_amdgcn_update_dpp(0, __float_as_int(x), 0x4E, 0xf, 0xf, true);
                    x += __int_as_float(t1);
                    int t2 = __builtin_amdgcn_update_dpp(0, __float_as_int(x), 0x141, 0xf, 0xf, true);
                    x += __int_as_float(t2);
                    int t3 = __builtin_amdgcn_update_dpp(0, __float_as_int(x), 0x140, 0xf, 0xf, true);
                    x += __int_as_float(t3);
                    accA[mt][r] = x;
                }
#pragma unroll
            for (int j = 0; j < 12; ++j) {
                float x = accV[j];
                int t0 = __builtin_amdgcn_update_dpp(0, __float_as_int(x), 0xB1, 0xf, 0xf, true);
                x += __int_as_float(t0);
                int t1 = __builtin_amdgcn_update_dpp(0, __float_as_int(x), 0x4E, 0xf, 0xf, true);
                x += __int_as_float(t1);
                int t2 = __builtin_amdgcn_update_dpp(0, __float_as_int(x), 0x141, 0xf, 0xf, true);
                x += __int_as_float(t2);
                int t3 = __builtin_amdgcn_update_dpp(0, __float_as_int(x), 0x140, 0xf, 0xf, true);
                x += __int_as_float(t3);
                accV[j] = x;
            }
            if (col == 0) {
                // accA[mt][r] holds dim (mt>>1)*32 + quad*8 + (mt&1)*4 + r
#pragma unroll
                for (int mt = 0; mt < 4; ++mt) {
                    float4 st = {accA[mt][0], accA[mt][1], accA[mt][2], accA[mt][3]};
                    int off = (mt >> 1) * 32 + quad * 8 + (mt & 1) * 4;
                    *(float4*)&outA[(size_t)n_cur * 64 + off] = st;
                }
#pragma unroll
                for (int j = 0; j < 3; ++j) {
                    float4 st = {accV[j * 4 + 0], accV[j * 4 + 1], accV[j * 4 + 2], accV[j * 4 + 3]};
                    *(float4*)&outV[(size_t)n_cur * 48 + quad * 12 + j * 4] = st;
                }
            }
#pragma unroll
            for (int mt = 0; mt < 4; ++mt)
#pragma unroll
                for (int r = 0; r < 4; ++r) accA[mt][r] = 0.f;
#pragma unroll
            for (int j = 0; j < 12; ++j) accV[j] = 0.f;
        }

        // ---- shift
        n_cur = n_nxt; j_cur = j_nxt; deg_cur = dnx;
        rC0 = rN0; rC1 = rN1; rC2 = rN2;
        if (j_cur + 16 < deg_cur) { n_nxt = n_cur; j_nxt = j_cur + 16; }
        else                      { n_nxt = n_cur + NODE_STRIDE; j_nxt = 0; }
    }
}

extern "C" void kernel_launch(void* const* d_in, const int* in_sizes, int n_in,
                              void* d_out, int out_size, void* d_ws, size_t ws_size,
                              hipStream_t stream) {
    const float* r_ij  = (const float*)d_in[0];
    const float* x_a   = (const float*)d_in[1];
    const float* x_v   = (const float*)d_in[2];
    const int*   src   = (const int*)d_in[3];
    const int*   dst   = (const int*)d_in[4];
    const float* W_L0  = (const float*)d_in[5];
    const float* W_L1  = (const float*)d_in[6];
    const float* W_enc = (const float*)d_in[7];
    const float* b_enc = (const float*)d_in[8];
    const float* WY000 = (const float*)d_in[9];
    const float* WY110 = (const float*)d_in[10];
    const float* WY011 = (const float*)d_in[11];
    const float* WY101 = (const float*)d_in[12];
    const float* WY111 = (const float*)d_in[13];
    const float* Wm1   = (const float*)d_in[14];
    const float* bm1   = (const float*)d_in[15];
    const float* Wm2   = (const float*)d_in[16];
    const float* bm2   = (const float*)d_in[17];
    const float* Wm3   = (const float*)d_in[18];
    float* out = (float*)d_out;

    char* ws = (char*)d_ws;
    unsigned short* rec = (unsigned short*)(ws + REC_OFF);
    int* cnt            = (int*)(ws + CNT_OFF);
    int* ellp           = (int*)(ws + ELLP_OFF);

    (void)hipMemsetAsync(cnt, 0, N_NODES * sizeof(int), stream);
    pre_kernel<<<7032, 256, 0, stream>>>(x_a, x_v, W_L0, W_L1, src,
                                         rec, cnt, ellp);
    node_major_kernel<<<768, 256, 0, stream>>>(ellp, r_ij, dst, W_enc, b_enc,
            WY000, WY110, WY011, WY101, WY111, Wm1, bm1, Wm2, bm2, Wm3,
            rec, cnt, out);
}

// Round 12
// 313.678 us; speedup vs baseline: 1.1015x; 1.1015x over previous
//
#include <hip/hip_runtime.h>

typedef _Float16 f16x8 __attribute__((ext_vector_type(8)));
typedef _Float16 f16x2 __attribute__((ext_vector_type(2)));
typedef float f32x4 __attribute__((ext_vector_type(4)));
typedef float f32x8 __attribute__((ext_vector_type(8)));

#define N_NODES 50000
#define N_EDGES 800000
#define MAXDEG 128
#define NODE_STRIDE 3072          // grid 768 blocks x 4 waves
#define BA_OFF 0
#define BV_OFF (N_NODES * 64)

// ---- workspace layout (byte offsets)
#define REC_OFF   0ull            // 50000*128 fp16 = 12.8 MB node records
#define CNT_OFF   12800000ull     // 50000 int degree counts
#define ELLP_OFF  13200384ull     // 50000*128 int4 {r0,r1,r2,dst} = 102.4 MB

// ---- LDS weight layout (ushort units, fp16). K=64 rows padded to 72, K=32 to 40
// Rows of WFOLD sigma-permuted, rows of WCAT/WM1/WM2/WM3 sigma2-permuted so
// every MFMA C-output lands directly in the B-fragment layout of its consumer.
#define OFF_WFOLD 0              // 32 x 40
#define OFF_WCAT  1280           // 64 x 72  [WY000 | WY110]
#define OFF_W011  5888           // 16 x 40
#define OFF_WV    6528           // 16 x 72  [WY101 | WY111]
#define OFF_WM1   7680           // 64 x 72
#define OFF_WM2   12288
#define OFF_WM3   16896
#define W_USHORTS 21504

__device__ __forceinline__ unsigned short f2h(float x) {
    _Float16 h = (_Float16)x;
    union { _Float16 h; unsigned short u; } c; c.h = h;
    return c.u;
}
__device__ __forceinline__ f16x2 pkrtz(float a, float b) {
    auto r = __builtin_amdgcn_cvt_pkrtz(a, b);   // __fp16 ext_vector(2)
    union { decltype(r) i; f16x2 o; } c; c.i = r;
    return c.o;
}
__device__ __forceinline__ f16x2 as_h2(unsigned u) {
    union { unsigned u; f16x2 h; } c; c.u = u; return c.h;
}
__device__ __forceinline__ unsigned h2_pack(float a, float b) {
    union { f16x2 h; unsigned u; } c;
    c.h = pkrtz(a, b);
    return c.u;
}
__device__ __forceinline__ f16x8 mk8(f16x2 a, f16x2 b, f16x2 c, f16x2 d) {
    union { f16x2 p[4]; f16x8 v; } u;
    u.p[0] = a; u.p[1] = b; u.p[2] = c; u.p[3] = d;
    return u.v;
}
__device__ __forceinline__ f16x8 as_f16x8(uint4 q) {
    union { uint4 u; f16x8 h; } c; c.u = q; return c.h;
}
// packed leaky-relu on 2 halves
__device__ __forceinline__ f16x2 leaky2(f16x2 x) {
    return __builtin_elementwise_max(x, x * (_Float16)0.1f);
}

// ---------------- fused pre-pass: node features + ELL build in one dispatch.
// Node phase: W_L0/W_L1 staged in PADDED LDS ([32][65]/[32][17], bank=(c+k)%32)
// — the direct per-lane c*64-strided global reads were a 32-line-per-instr L1
// thrash (the dominant unmodeled pre-pass cost). cnt zeroed by hipMemsetAsync.
__global__ __launch_bounds__(256) void pre_kernel(
    const float* __restrict__ x_a, const float* __restrict__ x_v,
    const float* __restrict__ W_L0, const float* __restrict__ W_L1,
    const int* __restrict__ src, const int* __restrict__ dst,
    const float* __restrict__ r_ij,
    unsigned short* __restrict__ rec, int* __restrict__ cnt,
    int4* __restrict__ ellp)
{
    __shared__ float WL0s[32 * 65];
    __shared__ float WL1s[32 * 17];
    int b = blockIdx.x;
    if (b % 3 == 0) {
        // ---- edge block: packed ELL build, each slot {r0,r1,r2,dst} (16B).
        // Loads issued before the atomic so they overlap its latency.
        int e = (b / 3) * 256 + threadIdx.x;   // 3125 blocks * 256 = 800000 exact
        if (e >= N_EDGES) return;
        int s = src[e];
        int4 v;
        v.x = __float_as_int(r_ij[e * 3 + 0]);
        v.y = __float_as_int(r_ij[e * 3 + 1]);
        v.z = __float_as_int(r_ij[e * 3 + 2]);
        v.w = dst[e];
        int o = atomicAdd(&cnt[s], 1);
        if (o < MAXDEG) {
            ellp[(size_t)s * MAXDEG + o] = v;
        }
    } else {
        // ---- node block: fp16 node records; weights from padded LDS
        const int tid = threadIdx.x;
        for (int i = tid; i < 2048; i += 256) {
            int c = i >> 6, k = i & 63;
            WL0s[c * 65 + k] = W_L0[i];
        }
        for (int i = tid; i < 512; i += 256) {
            int c = i >> 4, k = i & 15;
            WL1s[c * 17 + k] = W_L1[i];
        }
        __syncthreads();

        int nb = b - (b / 3 + 1);              // 6250 node blocks
        int t = nb * 256 + tid;
        int n = t >> 5, c = t & 31;
        const float4* xa = (const float4*)(x_a + (size_t)n * 64);
        const float* w0 = &WL0s[c * 65];
        float accA = 0.f;
#pragma unroll
        for (int k = 0; k < 16; ++k) {
            float4 a = xa[k];
            accA += a.x * w0[k * 4 + 0] + a.y * w0[k * 4 + 1]
                  + a.z * w0[k * 4 + 2] + a.w * w0[k * 4 + 3];
        }
        const float4* xv = (const float4*)(x_v + (size_t)n * 48);
        const float* w1 = &WL1s[c * 17];
        float a0 = 0.f, a1 = 0.f, a2 = 0.f;
#pragma unroll
        for (int g = 0; g < 4; ++g) {
            float4 v0 = xv[g * 3 + 0], v1 = xv[g * 3 + 1], v2 = xv[g * 3 + 2];
            float wA = w1[g * 4 + 0], wB = w1[g * 4 + 1], wC = w1[g * 4 + 2], wD = w1[g * 4 + 3];
            a0 += v0.x * wA; a1 += v0.y * wA; a2 += v0.z * wA;
            a0 += v0.w * wB; a1 += v1.x * wB; a2 += v1.y * wB;
            a0 += v1.z * wC; a1 += v1.w * wC; a2 += v2.x * wC;
            a0 += v2.y * wD; a1 += v2.z * wD; a2 += v2.w * wD;
        }
        unsigned short* rp = rec + (size_t)n * 128;
        rp[c]      = f2h(accA);
        rp[32 + c] = f2h(a0);
        rp[64 + c] = f2h(a1);
        rp[96 + c] = f2h(a2);
    }
}

// ---------------- node-major fused kernel: fp16 packed-math edition (round-10
// form: 16B ELL slots carry r+dst; rec quads prefetched one tile ahead).
// Bias in LDS as packed f16x2 (b_enc [0,16), bm1 [16,48), bm2 [48,80)).
// __launch_bounds__(256, 1): raising the bound makes the allocator spill
// (r1/r2 regression). VGPR must stay <= 170 for 3 waves/SIMD.
__global__ __launch_bounds__(256, 1) void node_major_kernel(
    const int4* __restrict__ ellp,
    const float* __restrict__ W_enc, const float* __restrict__ b_enc,
    const float* __restrict__ WY000, const float* __restrict__ WY110,
    const float* __restrict__ WY011, const float* __restrict__ WY101, const float* __restrict__ WY111,
    const float* __restrict__ Wm1, const float* __restrict__ bm1,
    const float* __restrict__ Wm2, const float* __restrict__ bm2,
    const float* __restrict__ Wm3,
    const unsigned short* __restrict__ rec,
    const int* __restrict__ cnt,
    float* __restrict__ out)
{
    __shared__ __align__(16) unsigned short Wlds[W_USHORTS];
    __shared__ __align__(8) unsigned BiasH[80];   // 160 f16 biases as f16x2 pairs

    const int tid = threadIdx.x;

    // ---- stage weights to LDS (fp16), fold W_enc over duplicated coeffs.
    // sigma  (32-chan): row i holds chan  c = ((i>>2)&3)*8 + (i>>4)*4 + (i&3)
    // sigma2 (64-dim) : row i holds dim   d = (i>>5)*32 + ((i>>2)&3)*8 + ((i>>4)&1)*4 + (i&3)
    for (int idx = tid; idx < 1024; idx += 256) {
        int i = idx >> 5, k = idx & 31;
        int c = ((i >> 2) & 3) * 8 + (i >> 4) * 4 + (i & 3);
        float v;
        if (k < 16) v = W_enc[c * 64 + 2 * k] + W_enc[c * 64 + 2 * k + 1];
        else        v = W_enc[c * 64 + 32 + 2 * (k - 16)] + W_enc[c * 64 + 32 + 2 * (k - 16) + 1];
        Wlds[OFF_WFOLD + i * 40 + k] = f2h(v);
    }
    for (int idx = tid; idx < 4096; idx += 256) {
        int i = idx >> 6, k = idx & 63;
        int d = (i >> 5) * 32 + ((i >> 2) & 3) * 8 + ((i >> 4) & 1) * 4 + (i & 3);
        float v = (k < 32) ? WY000[d * 32 + k] : WY110[d * 32 + (k - 32)];
        Wlds[OFF_WCAT + i * 72 + k] = f2h(v);
        Wlds[OFF_WM1 + i * 72 + k] = f2h(Wm1[d * 64 + k]);
        Wlds[OFF_WM2 + i * 72 + k] = f2h(Wm2[d * 64 + k]);
        Wlds[OFF_WM3 + i * 72 + k] = f2h(Wm3[d * 64 + k]);
    }
    for (int idx = tid; idx < 512; idx += 256) {
        int vv = idx >> 5, k = idx & 31;
        Wlds[OFF_W011 + vv * 40 + k] = f2h(WY011[vv * 32 + k]);
    }
    for (int idx = tid; idx < 1024; idx += 256) {
        int vv = idx >> 6, k = idx & 63;
        float w = (k < 32) ? WY101[vv * 32 + k] : WY111[vv * 32 + (k - 32)];
        Wlds[OFF_WV + vv * 72 + k] = f2h(w);
    }
    if (tid < 80) {
        float bv[2];
#pragma unroll
        for (int p = 0; p < 2; ++p) {
            int i = tid * 2 + p;
            float v;
            if (i < 32) {
                int c = ((i >> 2) & 3) * 8 + (i >> 4) * 4 + (i & 3);
                v = b_enc[c];
            } else {
                int ii = (i < 96) ? (i - 32) : (i - 96);
                int d = (ii >> 5) * 32 + ((ii >> 2) & 3) * 8 + ((ii >> 4) & 1) * 4 + (ii & 3);
                v = (i < 96) ? bm1[d] : bm2[d];
            }
            bv[p] = v;
        }
        BiasH[tid] = h2_pack(bv[0], bv[1]);
    }
    __syncthreads();

    const int wid  = tid >> 6;
    const int lane = tid & 63;
    const int col  = lane & 15;
    const int quad = lane >> 4;

    const f32x4 zero = {0.f, 0.f, 0.f, 0.f};
    float* __restrict__ outA = out + BA_OFF;
    float* __restrict__ outV = out + BV_OFF;

    // ---- hoist loop-invariant fragments (12 VGPR): W011 + WV
    const f16x8 a011R = *(const f16x8*)&Wlds[OFF_W011 + col * 40 + quad * 8];
    const f16x8 av0R  = *(const f16x8*)&Wlds[OFF_WV + col * 72 + quad * 8];
    const f16x8 av1R  = *(const f16x8*)&Wlds[OFF_WV + col * 72 + 32 + quad * 8];

    // ---- prologue
    int n_cur = blockIdx.x * 4 + wid, j_cur = 0;
    int deg_cur = cnt[n_cur]; deg_cur = (deg_cur < MAXDEG) ? deg_cur : MAXDEG;
    int4 hc = ellp[(size_t)n_cur * MAXDEG + col];
    int n_nxt, j_nxt;
    if (16 < deg_cur) { n_nxt = n_cur; j_nxt = 16; } else { n_nxt = n_cur + NODE_STRIDE; j_nxt = 0; }

    // prefetch rec quads for the FIRST tile
    uint4 qaN, qv0N, qv1N, qv2N;
    {
        int nd0 = ((unsigned)hc.w < N_NODES) ? hc.w : 0;
        const uint4* rp0 = (const uint4*)(rec + (size_t)nd0 * 128);
        qaN  = rp0[quad];
        qv0N = rp0[4 + quad];
        qv1N = rp0[8 + quad];
        qv2N = rp0[12 + quad];
    }

    float accA[4][4];
    float accV[12];
#pragma unroll
    for (int mt = 0; mt < 4; ++mt)
#pragma unroll
        for (int r = 0; r < 4; ++r) accA[mt][r] = 0.f;
#pragma unroll
    for (int j = 0; j < 12; ++j) accV[j] = 0.f;

    while (n_cur < N_NODES) {
        // ---- consume prefetched rec quads (issued last tile; latency hidden)
        f16x8 la  = as_f16x8(qaN);
        f16x8 lv0 = as_f16x8(qv0N);
        f16x8 lv1 = as_f16x8(qv1N);
        f16x8 lv2 = as_f16x8(qv2N);

        // ---- next-tile head (16B coalesced) + next deg
        int ns = (n_nxt < N_NODES) ? n_nxt : 0;
        int4 hn = ellp[(size_t)ns * MAXDEG + j_nxt + col];
        int dnx = cnt[ns]; dnx = (dnx < MAXDEG) ? dnx : MAXDEG;

        const float validf = (j_cur + col < deg_cur) ? 1.f : 0.f;
        const float vf01 = 0.1f * validf;
        const _Float16 vh = (_Float16)validf;
        const f16x2 vh2 = {vh, vh};

        // ---- per-edge geometry (fast transcendentals)
        float r0 = __int_as_float(hc.x), r1 = __int_as_float(hc.y), r2 = __int_as_float(hc.z);
        float u  = sqrtf(r0 * r0 + r1 * r1 + r2 * r2);
        float a  = 0.6283185307f * u;            // (pi/5) * dist
        float s14 = 1.4f * u;
        float e2 = __expf(fminf(2.f * s14, 20.f));
        float f  = (e2 - 1.f) / ((e2 + 1.f) * fmaxf(s14, 1e-12f));
        float rh0 = 1.4f * r0 * f, rh1 = 1.4f * r1 * f, rh2 = 1.4f * r2 * f;
        _Float16 h0 = (_Float16)rh0, h1 = (_Float16)rh1, h2 = (_Float16)rh2;

        // ---- radial features: native sincos + dual-chain recurrence
        float c1, s1;
        __sincosf(a, &s1, &c1);
        float c2 = c1 * c1 - s1 * s1, s2 = 2.f * c1 * s1;
        float cc, ss;
        if (quad & 1) {
            float c4 = c2 * c2 - s2 * s2, s4 = 2.f * c2 * s2;
            float c8 = c4 * c4 - s4 * s4, s8 = 2.f * c4 * s4;
            cc = c8 * c1 - s8 * s1; ss = s8 * c1 + c8 * s1;   // harmonic 9
        } else { cc = c1; ss = s1; }                           // harmonic 1
        float ca = cc, sa = ss;
        float cb = cc * c1 - ss * s1, sb = ss * c1 + cc * s1;
        bool usec = (quad < 2);
        f32x8 rvf;
        rvf[0] = usec ? ca : sa;
        rvf[1] = usec ? cb : sb;
#pragma unroll
        for (int st = 0; st < 3; ++st) {
            float can = ca * c2 - sa * s2; sa = sa * c2 + ca * s2; ca = can;
            float cbn = cb * c2 - sb * s2; sb = sb * c2 + cb * s2; cb = cbn;
            rvf[2 + 2 * st] = usec ? ca : sa;
            rvf[3 + 2 * st] = usec ? cb : sb;
        }
        f16x8 brad = mk8(pkrtz(rvf[0], rvf[1]), pkrtz(rvf[2], rvf[3]),
                         pkrtz(rvf[4], rvf[5]), pkrtz(rvf[6], rvf[7]));

        // ---- phi GEMM: output lands as chans quad*8+j (sigma-permuted A rows)
        f16x8 phi8;
        {
            f16x8 aw0 = *(const f16x8*)&Wlds[OFF_WFOLD + col * 40 + quad * 8];
            f32x4 pa = __builtin_amdgcn_mfma_f32_16x16x32_f16(aw0, brad, zero, 0, 0, 0);
            f16x8 aw1 = *(const f16x8*)&Wlds[OFF_WFOLD + (16 + col) * 40 + quad * 8];
            f32x4 pb = __builtin_amdgcn_mfma_f32_16x16x32_f16(aw1, brad, zero, 0, 0, 0);
            uint2 b0 = *(const uint2*)&BiasH[quad * 2];
            uint2 b1 = *(const uint2*)&BiasH[8 + quad * 2];
            f16x2 p01 = (pkrtz(pa[0], pa[1]) + as_h2(b0.x)) * vh2;
            f16x2 p23 = (pkrtz(pa[2], pa[3]) + as_h2(b0.y)) * vh2;
            f16x2 p45 = (pkrtz(pb[0], pb[1]) + as_h2(b1.x)) * vh2;
            f16x2 p67 = (pkrtz(pb[2], pb[3]) + as_h2(b1.y)) * vh2;
            phi8 = mk8(p01, p23, p45, p67);
        }

        // ---- packed tensor products (v_pk_*_f16): plv shared by y1 and psi_v
        f16x8 plv0 = phi8 * lv0;
        f16x8 plv1 = phi8 * lv1;
        f16x8 plv2 = phi8 * lv2;
        f16x8 fy0 = la * phi8;                       // y000
        f16x8 fy1 = plv0 * h0 + plv1 * h1 + plv2 * h2;   // y110 = phi*(lv.rh)

        // ---- psi_a (output sigma2-permuted via WCAT row permutation)
        f32x4 pacc[4];
#pragma unroll
        for (int mt = 0; mt < 4; ++mt) {
            f16x8 a0 = *(const f16x8*)&Wlds[OFF_WCAT + (mt * 16 + col) * 72 + quad * 8];
            f16x8 a1 = *(const f16x8*)&Wlds[OFF_WCAT + (mt * 16 + col) * 72 + 32 + quad * 8];
            pacc[mt] = __builtin_amdgcn_mfma_f32_16x16x32_f16(a0, fy0, zero, 0, 0, 0);
            pacc[mt] = __builtin_amdgcn_mfma_f32_16x16x32_f16(a1, fy1, pacc[mt], 0, 0, 0);
        }
#pragma unroll
        for (int mt = 0; mt < 4; ++mt)
#pragma unroll
            for (int r = 0; r < 4; ++r)
                accA[mt][r] = fmaf(pacc[mt][r], vf01, accA[mt][r]);
        // psi -> MLP B fragments (dims quad*8+j and 32+quad*8+j)
        f16x8 fb0 = mk8(pkrtz(pacc[0][0], pacc[0][1]), pkrtz(pacc[0][2], pacc[0][3]),
                        pkrtz(pacc[1][0], pacc[1][1]), pkrtz(pacc[1][2], pacc[1][3]));
        f16x8 fb1 = mk8(pkrtz(pacc[2][0], pacc[2][1]), pkrtz(pacc[2][2], pacc[2][3]),
                        pkrtz(pacc[3][0], pacc[3][1]), pkrtz(pacc[3][2], pacc[3][3]));

        // ---- PREFETCH next tile's rec quads (hn returned by now; consumed
        // next iteration -> gather latency hidden under remaining compute)
        {
            int ndn = ((unsigned)hn.w < N_NODES) ? hn.w : 0;
            const uint4* rpn = (const uint4*)(rec + (size_t)ndn * 128);
            qaN  = rpn[quad];
            qv0N = rpn[4 + quad];
            qv1N = rpn[8 + quad];
            qv2N = rpn[12 + quad];
        }

        // ---- t011 (hoisted A fragment)
        f32x4 t011v = __builtin_amdgcn_mfma_f32_16x16x32_f16(a011R, fy0, zero, 0, 0, 0);
        f32x4 t01s;
#pragma unroll
        for (int r = 0; r < 4; ++r) t01s[r] = 0.1f * t011v[r];

        // ---- psi_v: q1 = plv (free), q2 = packed cross of plv with rh
        {
            f16x8 q2x = plv1 * h2 - plv2 * h1;
            f32x4 vx = __builtin_amdgcn_mfma_f32_16x16x32_f16(av0R, plv0, zero, 0, 0, 0);
            vx = __builtin_amdgcn_mfma_f32_16x16x32_f16(av1R, q2x, vx, 0, 0, 0);
#pragma unroll
            for (int r = 0; r < 4; ++r)
                accV[r * 3 + 0] = fmaf(0.1f, vx[r], fmaf(t01s[r], rh0, accV[r * 3 + 0]));

            f16x8 q2y = plv2 * h0 - plv0 * h2;
            f32x4 vy = __builtin_amdgcn_mfma_f32_16x16x32_f16(av0R, plv1, zero, 0, 0, 0);
            vy = __builtin_amdgcn_mfma_f32_16x16x32_f16(av1R, q2y, vy, 0, 0, 0);
#pragma unroll
            for (int r = 0; r < 4; ++r)
                accV[r * 3 + 1] = fmaf(0.1f, vy[r], fmaf(t01s[r], rh1, accV[r * 3 + 1]));

            f16x8 q2z = plv0 * h1 - plv1 * h0;
            f32x4 vz = __builtin_amdgcn_mfma_f32_16x16x32_f16(av0R, plv2, zero, 0, 0, 0);
            vz = __builtin_amdgcn_mfma_f32_16x16x32_f16(av1R, q2z, vz, 0, 0, 0);
#pragma unroll
            for (int r = 0; r < 4; ++r)
                accV[r * 3 + 2] = fmaf(0.1f, vz[r], fmaf(t01s[r], rh2, accV[r * 3 + 2]));
        }

        // ---- residual MLP (rows sigma2-permuted => register chaining)
        f32x4 hacc[4];
#pragma unroll
        for (int mt = 0; mt < 4; ++mt) {
            f16x8 a0 = *(const f16x8*)&Wlds[OFF_WM1 + (mt * 16 + col) * 72 + quad * 8];
            f16x8 a1 = *(const f16x8*)&Wlds[OFF_WM1 + (mt * 16 + col) * 72 + 32 + quad * 8];
            hacc[mt] = __builtin_amdgcn_mfma_f32_16x16x32_f16(a0, fb0, zero, 0, 0, 0);
            hacc[mt] = __builtin_amdgcn_mfma_f32_16x16x32_f16(a1, fb1, hacc[mt], 0, 0, 0);
        }
        f16x8 fh0, fh1;
        {
            uint2 bA = *(const uint2*)&BiasH[16 + 0 * 8 + quad * 2];
            uint2 bB = *(const uint2*)&BiasH[16 + 1 * 8 + quad * 2];
            uint2 bC = *(const uint2*)&BiasH[16 + 2 * 8 + quad * 2];
            uint2 bD = *(const uint2*)&BiasH[16 + 3 * 8 + quad * 2];
            fh0 = mk8(leaky2(pkrtz(hacc[0][0], hacc[0][1]) + as_h2(bA.x)),
                      leaky2(pkrtz(hacc[0][2], hacc[0][3]) + as_h2(bA.y)),
                      leaky2(pkrtz(hacc[1][0], hacc[1][1]) + as_h2(bB.x)),
                      leaky2(pkrtz(hacc[1][2], hacc[1][3]) + as_h2(bB.y)));
            fh1 = mk8(leaky2(pkrtz(hacc[2][0], hacc[2][1]) + as_h2(bC.x)),
                      leaky2(pkrtz(hacc[2][2], hacc[2][3]) + as_h2(bC.y)),
                      leaky2(pkrtz(hacc[3][0], hacc[3][1]) + as_h2(bD.x)),
                      leaky2(pkrtz(hacc[3][2], hacc[3][3]) + as_h2(bD.y)));
        }

        f32x4 gacc[4];
#pragma unroll
        for (int mt = 0; mt < 4; ++mt) {
            f16x8 a0 = *(const f16x8*)&Wlds[OFF_WM2 + (mt * 16 + col) * 72 + quad * 8];
            f16x8 a1 = *(const f16x8*)&Wlds[OFF_WM2 + (mt * 16 + col) * 72 + 32 + quad * 8];
            gacc[mt] = __builtin_amdgcn_mfma_f32_16x16x32_f16(a0, fh0, zero, 0, 0, 0);
            gacc[mt] = __builtin_amdgcn_mfma_f32_16x16x32_f16(a1, fh1, gacc[mt], 0, 0, 0);
        }
        f16x8 fg0, fg1;
        {
            // bm2 biases live at BiasH[48..80)
            uint2 bA = *(const uint2*)&BiasH[48 + 0 * 8 + quad * 2];
            uint2 bB = *(const uint2*)&BiasH[48 + 1 * 8 + quad * 2];
            uint2 bC = *(const uint2*)&BiasH[48 + 2 * 8 + quad * 2];
            uint2 bD = *(const uint2*)&BiasH[48 + 3 * 8 + quad * 2];
            fg0 = mk8(leaky2(pkrtz(gacc[0][0], gacc[0][1]) + as_h2(bA.x)),
                      leaky2(pkrtz(gacc[0][2], gacc[0][3]) + as_h2(bA.y)),
                      leaky2(pkrtz(gacc[1][0], gacc[1][1]) + as_h2(bB.x)),
                      leaky2(pkrtz(gacc[1][2], gacc[1][3]) + as_h2(bB.y)));
            fg1 = mk8(leaky2(pkrtz(gacc[2][0], gacc[2][1]) + as_h2(bC.x)),
                      leaky2(pkrtz(gacc[2][2], gacc[2][3]) + as_h2(bC.y)),
                      leaky2(pkrtz(gacc[3][0], gacc[3][1]) + as_h2(bD.x)),
                      leaky2(pkrtz(gacc[3][2], gacc[3][3]) + as_h2(bD.y)));
        }

#pragma unroll
        for (int mt = 0; mt < 4; ++mt) {
            f16x8 a0 = *(const f16x8*)&Wlds[OFF_WM3 + (mt * 16 + col) * 72 + quad * 8];
            f16x8 a1 = *(const f16x8*)&Wlds[OFF_WM3 + (mt * 16 + col) * 72 + 32 + quad * 8];
            f32x4 oacc = __builtin_amdgcn_mfma_f32_16x16x32_f16(a0, fg0, zero, 0, 0, 0);
            oacc = __builtin_amdgcn_mfma_f32_16x16x32_f16(a1, fg1, oacc, 0, 0, 0);
#pragma unroll
            for (int r = 0; r < 4; ++r)
                accA[mt][r] = fmaf(oacc[r], vf01, accA[mt][r]);
        }

        // ---- node boundary: DPP reduce over the 16 cols + store + reset
        if (n_nxt != n_cur) {
#pragma unroll
            for (int mt = 0; mt < 4; ++mt)
#pragma unroll
                for (int r = 0; r < 4; ++r) {
                    float x = accA[mt][r];
                    int t0 = __builtin_amdgcn_update_dpp(0, __float_as_int(x), 0xB1, 0xf, 0xf, true);
                    x += __int_as_float(t0);
                    int t1 = __builtin_amdgcn_update_dpp(0, __float_as_int(x), 0x4E, 0xf, 0xf, true);
                    x += __int_as_float(t1);
                    int t2 = __builtin_amdgcn_update_dpp(0, __float_as_int(x), 0x141, 0xf, 0xf, true);
                    x += __int_as_float(t2);
                    int t3 = __builtin_amdgcn_update_dpp(0, __float_as_int(x), 0x140, 0xf, 0xf, true);
                    x += __int_as_float(t3);
                    accA[mt][r] = x;
                }
#pragma unroll
            for (int j = 0; j < 12; ++j) {
                float x = accV[j];
                int t0 = __builtin_amdgcn_update_dpp(0, __float_as_int(x), 0xB1, 0xf, 0xf, true);
                x += __int_as_float(t0);
                int t1 = __builtin_amdgcn_update_dpp(0, __float_as_int(x), 0x4E, 0xf, 0xf, true);
                x += __int_as_float(t1);
                int t2 = __builtin_amdgcn_update_dpp(0, __float_as_int(x), 0x141, 0xf, 0xf, true);
                x += __int_as_float(t2);
                int t3 = __builtin_amdgcn_update_dpp(0, __float_as_int(x), 0x140, 0xf, 0xf, true);
                x += __int_as_float(t3);
                accV[j] = x;
            }
            if (col == 0) {
                // accA[mt][r] holds dim (mt>>1)*32 + quad*8 + (mt&1)*4 + r
#pragma unroll
                for (int mt = 0; mt < 4; ++mt) {
                    float4 st = {accA[mt][0], accA[mt][1], accA[mt][2], accA[mt][3]};
                    int off = (mt >> 1) * 32 + quad * 8 + (mt & 1) * 4;
                    *(float4*)&outA[(size_t)n_cur * 64 + off] = st;
                }
#pragma unroll
                for (int j = 0; j < 3; ++j) {
                    float4 st = {accV[j * 4 + 0], accV[j * 4 + 1], accV[j * 4 + 2], accV[j * 4 + 3]};
                    *(float4*)&outV[(size_t)n_cur * 48 + quad * 12 + j * 4] = st;
                }
            }
#pragma unroll
            for (int mt = 0; mt < 4; ++mt)
#pragma unroll
                for (int r = 0; r < 4; ++r) accA[mt][r] = 0.f;
#pragma unroll
            for (int j = 0; j < 12; ++j) accV[j] = 0.f;
        }

        // ---- shift
        n_cur = n_nxt; j_cur = j_nxt; deg_cur = dnx; hc = hn;
        if (j_cur + 16 < deg_cur) { n_nxt = n_cur; j_nxt = j_cur + 16; }
        else                      { n_nxt = n_cur + NODE_STRIDE; j_nxt = 0; }
    }
}

extern "C" void kernel_launch(void* const* d_in, const int* in_sizes, int n_in,
                              void* d_out, int out_size, void* d_ws, size_t ws_size,
                              hipStream_t stream) {
    const float* r_ij  = (const float*)d_in[0];
    const float* x_a   = (const float*)d_in[1];
    const float* x_v   = (const float*)d_in[2];
    const int*   src   = (const int*)d_in[3];
    const int*   dst   = (const int*)d_in[4];
    const float* W_L0  = (const float*)d_in[5];
    const float* W_L1  = (const float*)d_in[6];
    const float* W_enc = (const float*)d_in[7];
    const float* b_enc = (const float*)d_in[8];
    const float* WY000 = (const float*)d_in[9];
    const float* WY110 = (const float*)d_in[10];
    const float* WY011 = (const float*)d_in[11];
    const float* WY101 = (const float*)d_in[12];
    const float* WY111 = (const float*)d_in[13];
    const float* Wm1   = (const float*)d_in[14];
    const float* bm1   = (const float*)d_in[15];
    const float* Wm2   = (const float*)d_in[16];
    const float* bm2   = (const float*)d_in[17];
    const float* Wm3   = (const float*)d_in[18];
    float* out = (float*)d_out;

    char* ws = (char*)d_ws;
    unsigned short* rec = (unsigned short*)(ws + REC_OFF);
    int* cnt            = (int*)(ws + CNT_OFF);
    int4* ellp          = (int4*)(ws + ELLP_OFF);

    (void)hipMemsetAsync(cnt, 0, N_NODES * sizeof(int), stream);
    pre_kernel<<<9375, 256, 0, stream>>>(x_a, x_v, W_L0, W_L1, src, dst, r_ij,
                                         rec, cnt, ellp);
    node_major_kernel<<<768, 256, 0, stream>>>(ellp, W_enc, b_enc,
            WY000, WY110, WY011, WY101, WY111, Wm1, bm1, Wm2, bm2, Wm3,
            rec, cnt, out);
}